// Round 4
// baseline (965.194 us; speedup 1.0000x reference)
//
#include <hip/hip_runtime.h>
#include <stdint.h>

#define FEAT 512
#define HID  256
#define TILE 64
#define G1   512   // fused_main grid (2 blocks/CU on 256 CUs)

typedef __attribute__((ext_vector_type(8))) short   short8;
typedef __attribute__((ext_vector_type(4))) float   floatx4;
typedef unsigned int u32;

__device__ inline unsigned short f2bf(float x){
  union { float f; uint32_t u; } v; v.f = x;
  uint32_t u = v.u;
  u += 0x7FFFu + ((u >> 16) & 1u);      // round-to-nearest-even
  return (unsigned short)(u >> 16);
}
__device__ inline float bf2f(unsigned short h){
  union { uint32_t u; float f; } v; v.u = ((uint32_t)h) << 16;
  return v.f;
}
__device__ inline float sigm_f(float x){ return 1.f/(1.f + __expf(-x)); }
__device__ inline float tanh_f(float x){ return 2.f/(1.f + __expf(-2.f*x)) - 1.f; }

__device__ inline short8 pack_bf8(float4 a, float4 b){
  union { short8 v; unsigned short u[8]; } r;
  r.u[0]=f2bf(a.x); r.u[1]=f2bf(a.y); r.u[2]=f2bf(a.z); r.u[3]=f2bf(a.w);
  r.u[4]=f2bf(b.x); r.u[5]=f2bf(b.y); r.u[6]=f2bf(b.z); r.u[7]=f2bf(b.w);
  return r.v;
}

// async global->LDS, 16B per lane; lds dst must be wave-uniform (HW adds lane*16)
__device__ __forceinline__ void gl_lds16(const void* g, void* l){
  __builtin_amdgcn_global_load_lds(
      (const __attribute__((address_space(1))) u32*)g,
      (__attribute__((address_space(3))) u32*)l, 16, 0, 0);
}

#define SCHED_FENCE() __builtin_amdgcn_sched_barrier(0)

// ---------------------------------------------------------------------------
// prep: W[K][256] fp32 row-major -> bf16 swizzled to MFMA B-fragment order:
// dst[((kb*16+nt)*64+lane)*8+j] = W[kb*32+(lane>>4)*8+j][nt*16+(lane&15)]
// ---------------------------------------------------------------------------
__global__ void prep_weights(const float* __restrict__ W1, const float* __restrict__ Wa,
                             const float* __restrict__ Wb,
                             unsigned short* __restrict__ W1bf,
                             unsigned short* __restrict__ Wabf,
                             unsigned short* __restrict__ Wbbf){
  int t = blockIdx.x*256 + threadIdx.x;
  const float* src; unsigned short* dst; int g;
  if      (t < 16384){ src = W1; dst = W1bf; g = t; }          // 16 kb * 16 nt * 64
  else if (t < 24576){ src = Wa; dst = Wabf; g = t - 16384; }  // 8 kb
  else if (t < 32768){ src = Wb; dst = Wbbf; g = t - 24576; }  // 8 kb
  else return;
  int lane = g & 63, nt = (g >> 6) & 15, kb = g >> 10;
  int col  = nt*16 + (lane & 15);
  int row0 = kb*32 + (lane >> 4)*8;
  unsigned short* d = dst + (size_t)g*8;
  const float*    s = src + (size_t)row0*HID + col;
  #pragma unroll
  for (int j = 0; j < 8; ++j) d[j] = f2bf(s[(size_t)j*HID]);
}

// ---------------------------------------------------------------------------
// fused_main: per 64-token tile: h=relu(x@W1+b1); a=tanh(h@Wa+ba);
// b=sigm(h@Wb+bb); s=(a*b)@Wc+bc; online softmax accumulate (m,l,g[256]).
// Weight staging: double-buffered LDS via global_load_lds, one-step-ahead
// prefetch, raw s_barrier + counted vmcnt (T3/T4 minimum-2-phase schedule).
// ---------------------------------------------------------------------------
__global__ __launch_bounds__(256, 2) void fused_main(
    const float* __restrict__ x,
    const float* __restrict__ b1, const float* __restrict__ ba,
    const float* __restrict__ bb, const float* __restrict__ Wc,
    const float* __restrict__ bc,
    const unsigned short* __restrict__ W1bf,
    const unsigned short* __restrict__ Wabf,
    const unsigned short* __restrict__ Wbbf,
    float* __restrict__ s_buf, float* __restrict__ partials, int ntiles)
{
  __shared__ alignas(16) unsigned short Hs[64][264];   // 64 tokens x 256 h (+8 pad)
  __shared__ alignas(16) unsigned short Ws[2][8192];   // 2 x 16KB weight staging
  __shared__ float pbuf[4][16];

  const int tid  = threadIdx.x;
  const int wave = tid >> 6, lane = tid & 63;
  const int quad = lane >> 4, l15 = lane & 15;

  float m_run = -INFINITY, l_run = 0.f;
  float g0 = 0.f, g1 = 0.f, g2 = 0.f, g3 = 0.f;   // cols 4*lane .. 4*lane+3
  const float bcv = bc[0];

  for (int t = blockIdx.x; t < ntiles; t += gridDim.x){
    const int tokw = t*TILE + wave*16;

    // ---- x preload & pack to bf16 (fully unrolled: static xf indexing) ----
    short8 xf[16];
    {
      const float* xr = x + (size_t)(tokw + l15)*FEAT + quad*8;
      #pragma unroll
      for (int kb = 0; kb < 16; ++kb){
        float4 a = *(const float4*)(xr + kb*32);
        float4 b = *(const float4*)(xr + kb*32 + 4);
        xf[kb] = pack_bf8(a, b);
      }
    }

    // ---------------- GEMM1: h = relu(x @ W1 + b1), K=512 ----------------
    floatx4 acc[16];
    #pragma unroll
    for (int nt = 0; nt < 16; ++nt){
      float bv = b1[nt*16 + l15];
      floatx4 tmp = {bv, bv, bv, bv};
      acc[nt] = tmp;
    }
    // stage kb=0 -> Ws[0]  (each wave: 4 x 1KB chunks)
    #pragma unroll
    for (int c = 0; c < 4; ++c)
      gl_lds16(W1bf + (wave*4 + c)*512 + lane*8, &Ws[0][(wave*4 + c)*512]);

    #pragma unroll
    for (int kb = 0; kb < 16; ++kb){
      if (kb < 15){
        const unsigned short* src = W1bf + (size_t)(kb+1)*8192;
        unsigned short* dst = Ws[(kb+1) & 1];
        #pragma unroll
        for (int c = 0; c < 4; ++c)
          gl_lds16(src + (wave*4 + c)*512 + lane*8, dst + (wave*4 + c)*512);
        SCHED_FENCE();
        asm volatile("s_waitcnt vmcnt(4)" ::: "memory");   // cur buffer landed
      } else {
        SCHED_FENCE();
        asm volatile("s_waitcnt vmcnt(0)" ::: "memory");
      }
      __builtin_amdgcn_s_barrier();       // all waves: cur buffer ready
      SCHED_FENCE();
      const unsigned short* wsb = Ws[kb & 1];
      #pragma unroll
      for (int nt = 0; nt < 16; ++nt){
        short8 wf = *(const short8*)(wsb + nt*512 + lane*8);
        acc[nt] = __builtin_amdgcn_mfma_f32_16x16x32_bf16(xf[kb], wf, acc[nt], 0, 0, 0);
      }
      SCHED_FENCE();
      __builtin_amdgcn_s_barrier();       // release cur for overwrite
    }

    // stage GEMM2 step 0 (Wa/Wb block kb=0,nh=0) -> Ws[0] early, then Hs epilogue
    #pragma unroll
    for (int c = 0; c < 4; ++c){
      int chunk = wave*4 + c;
      const unsigned short* s8 = (chunk < 8) ? (Wabf + chunk*512)
                                             : (Wbbf + (chunk-8)*512);
      gl_lds16(s8 + lane*8, &Ws[0][chunk*512]);
    }
    #pragma unroll
    for (int nt = 0; nt < 16; ++nt){
      #pragma unroll
      for (int r = 0; r < 4; ++r)
        Hs[wave*16 + quad*4 + r][nt*16 + l15] = f2bf(fmaxf(acc[nt][r], 0.f));
    }

    // ---- GEMM2: a=tanh(h@Wa+ba), b=sigm(h@Wb+bb), s=(a*b)@Wc+bc, K=256 ----
    float sp0 = 0.f, sp1 = 0.f, sp2 = 0.f, sp3 = 0.f;
    #pragma unroll 1
    for (int nh = 0; nh < 2; ++nh){
      floatx4 aacc[8], bacc[8];
      #pragma unroll
      for (int nt = 0; nt < 8; ++nt){
        int col = (nh*8 + nt)*16 + l15;
        float av = ba[col], bv = bb[col];
        floatx4 ta = {av, av, av, av}; aacc[nt] = ta;
        floatx4 tb = {bv, bv, bv, bv}; bacc[nt] = tb;
      }
      #pragma unroll 1
      for (int kb = 0; kb < 8; ++kb){
        int s = nh*8 + kb;                 // global step 0..15, buffer = Ws[s&1]
        if (s < 15){
          int s2 = s + 1, nh2 = s2 >> 3, kb2 = s2 & 7;
          const unsigned short* srcA = Wabf + (size_t)(kb2*16 + nh2*8)*512;
          const unsigned short* srcB = Wbbf + (size_t)(kb2*16 + nh2*8)*512;
          unsigned short* dst = Ws[s2 & 1];
          #pragma unroll
          for (int c = 0; c < 4; ++c){
            int chunk = wave*4 + c;
            const unsigned short* s8 = (chunk < 8) ? (srcA + chunk*512)
                                                   : (srcB + (chunk-8)*512);
            gl_lds16(s8 + lane*8, dst + chunk*512);
          }
          SCHED_FENCE();
          asm volatile("s_waitcnt vmcnt(4)" ::: "memory");
        } else {
          SCHED_FENCE();
          asm volatile("s_waitcnt vmcnt(0)" ::: "memory");
        }
        __builtin_amdgcn_s_barrier();
        SCHED_FENCE();
        const unsigned short* wsb = Ws[s & 1];
        short8 hf = *(const short8*)&Hs[wave*16 + l15][kb*32 + quad*8];
        #pragma unroll
        for (int nt = 0; nt < 8; ++nt){
          short8 wfa = *(const short8*)(wsb + nt*512 + lane*8);
          short8 wfb = *(const short8*)(wsb + 4096 + nt*512 + lane*8);
          aacc[nt] = __builtin_amdgcn_mfma_f32_16x16x32_bf16(hf, wfa, aacc[nt], 0, 0, 0);
          bacc[nt] = __builtin_amdgcn_mfma_f32_16x16x32_bf16(hf, wfb, bacc[nt], 0, 0, 0);
        }
        SCHED_FENCE();
        __builtin_amdgcn_s_barrier();
      }
      #pragma unroll
      for (int nt = 0; nt < 8; ++nt){
        float wcv = Wc[(nh*8 + nt)*16 + l15];
        sp0 += tanh_f(aacc[nt][0]) * sigm_f(bacc[nt][0]) * wcv;
        sp1 += tanh_f(aacc[nt][1]) * sigm_f(bacc[nt][1]) * wcv;
        sp2 += tanh_f(aacc[nt][2]) * sigm_f(bacc[nt][2]) * wcv;
        sp3 += tanh_f(aacc[nt][3]) * sigm_f(bacc[nt][3]) * wcv;
      }
    }
    // reduce s across the 16 lanes of each l15-group (rows = quad*4+r)
    #pragma unroll
    for (int mk = 1; mk < 16; mk <<= 1){
      sp0 += __shfl_xor(sp0, mk, 64);
      sp1 += __shfl_xor(sp1, mk, 64);
      sp2 += __shfl_xor(sp2, mk, 64);
      sp3 += __shfl_xor(sp3, mk, 64);
    }
    float s0 = sp0 + bcv, s1 = sp1 + bcv, s2 = sp2 + bcv, s3 = sp3 + bcv;
    if (l15 == 0){
      float* sb = s_buf + tokw + quad*4;
      sb[0] = s0; sb[1] = s1; sb[2] = s2; sb[3] = s3;
    }
    // online softmax update (per wave)
    float tmax = fmaxf(fmaxf(s0, s1), fmaxf(s2, s3));
    tmax = fmaxf(tmax, __shfl_xor(tmax, 16, 64));
    tmax = fmaxf(tmax, __shfl_xor(tmax, 32, 64));
    float m_new = fmaxf(m_run, tmax);
    float alpha = __expf(m_run - m_new);       // exp(-inf)=0 on first tile
    float p0 = __expf(s0 - m_new), p1 = __expf(s1 - m_new);
    float p2 = __expf(s2 - m_new), p3 = __expf(s3 - m_new);
    float psum = p0 + p1 + p2 + p3;
    psum += __shfl_xor(psum, 16, 64);
    psum += __shfl_xor(psum, 32, 64);          // sum over the 16 rows
    l_run = l_run*alpha + psum;
    m_run = m_new;
    if (l15 == 0){
      pbuf[wave][quad*4+0] = p0; pbuf[wave][quad*4+1] = p1;
      pbuf[wave][quad*4+2] = p2; pbuf[wave][quad*4+3] = p3;
    }
    g0 *= alpha; g1 *= alpha; g2 *= alpha; g3 *= alpha;
    #pragma unroll
    for (int rw = 0; rw < 16; ++rw){
      float pr = pbuf[wave][rw];
      const unsigned short* hp = &Hs[wave*16 + rw][lane*4];
      g0 += pr*bf2f(hp[0]); g1 += pr*bf2f(hp[1]);
      g2 += pr*bf2f(hp[2]); g3 += pr*bf2f(hp[3]);
    }
  }

  // ---- combine 4 waves -> per-workgroup partial {M, L, g[256]} ----
  __syncthreads();
  float* fred = (float*)Ws;                    // reuse staging LDS
  if (lane == 0) fred[wave] = m_run;
  __syncthreads();
  float M = fmaxf(fmaxf(fred[0], fred[1]), fmaxf(fred[2], fred[3]));
  float sc = (m_run == -INFINITY) ? 0.f : __expf(m_run - M);
  if (lane == 0) fred[4 + wave] = l_run * sc;
  fred[8 + wave*256 + lane*4 + 0] = g0*sc;
  fred[8 + wave*256 + lane*4 + 1] = g1*sc;
  fred[8 + wave*256 + lane*4 + 2] = g2*sc;
  fred[8 + wave*256 + lane*4 + 3] = g3*sc;
  __syncthreads();
  float gsum = fred[8 + 0*256 + tid] + fred[8 + 1*256 + tid]
             + fred[8 + 2*256 + tid] + fred[8 + 3*256 + tid];
  float* P = partials + (size_t)blockIdx.x*258;
  if (tid == 0){ P[0] = M; P[1] = fred[4] + fred[5] + fred[6] + fred[7]; }
  P[2 + tid] = gsum;
}

// ---------------------------------------------------------------------------
// reduce_heads: combine G1 partials -> M, L, global_feat; then hr/cls/reg
// heads in exact fp32. 1024 threads, split-K parallel matvecs.
// ---------------------------------------------------------------------------
__global__ __launch_bounds__(1024) void reduce_heads(const float* __restrict__ partials,
    const float* __restrict__ Wr,   const float* __restrict__ br,
    const float* __restrict__ Wcls, const float* __restrict__ bcls,
    const float* __restrict__ Wreg, const float* __restrict__ breg,
    float* __restrict__ out, float* __restrict__ ML, int ntok)
{
  __shared__ float red[1024];
  __shared__ float scw[G1];
  __shared__ float gf[256];
  __shared__ float hr[256];
  const int t = threadIdx.x;

  // M = max over partials
  float lm = -INFINITY;
  for (int i = t; i < G1; i += 1024) lm = fmaxf(lm, partials[(size_t)i*258]);
  red[t] = lm; __syncthreads();
  for (int s = 512; s > 0; s >>= 1){ if (t < s) red[t] = fmaxf(red[t], red[t+s]); __syncthreads(); }
  float M = red[0];
  __syncthreads();

  // L and per-partial scale weights
  float ll = 0.f;
  for (int i = t; i < G1; i += 1024){
    float w = __expf(partials[(size_t)i*258] - M);
    scw[i] = w;
    ll += partials[(size_t)i*258 + 1] * w;
  }
  red[t] = ll; __syncthreads();
  for (int s = 512; s > 0; s >>= 1){ if (t < s) red[t] += red[t+s]; __syncthreads(); }
  float L = red[0];
  __syncthreads();

  // global_feat: 4 i-groups of 256 cols
  const int col = t & 255, grp = t >> 8;
  float g = 0.f;
  #pragma unroll 4
  for (int i = grp; i < G1; i += 4) g += partials[(size_t)i*258 + 2 + col] * scw[i];
  red[t] = g; __syncthreads();
  if (grp == 0){
    float gfv = (red[col] + red[256+col] + red[512+col] + red[768+col]) / L;
    gf[col] = gfv;
    out[ntok + col] = gfv;
    if (col == 0){ ML[0] = M; ML[1] = 1.f / L; }
  }
  __syncthreads();

  // hr = relu(gf @ Wr + br): split K into 4 parts of 64
  float h = 0.f;
  #pragma unroll 8
  for (int c = grp*64; c < grp*64 + 64; ++c) h += gf[c] * Wr[(size_t)c*256 + col];
  red[t] = h; __syncthreads();
  if (grp == 0){
    float hv = red[col] + red[256+col] + red[512+col] + red[768+col] + br[col];
    hr[col] = fmaxf(hv, 0.f);
  }
  __syncthreads();

  // heads: 8 lanes per output, strided K, shfl-reduce
  const int o = t >> 3, sl = t & 7;
  if (o < 33){
    float v = 0.f;
    #pragma unroll 8
    for (int j = sl; j < 256; j += 8) v += hr[j] * Wcls[(size_t)j*33 + o];
    v += __shfl_xor(v, 1, 64); v += __shfl_xor(v, 2, 64); v += __shfl_xor(v, 4, 64);
    if (sl == 0) out[ntok + 256 + o] = v + bcls[o];
  } else if (o >= 64 && o < 64 + 55){
    int oo = o - 64;
    float v = 0.f;
    #pragma unroll 8
    for (int j = sl; j < 256; j += 8) v += hr[j] * Wreg[(size_t)j*55 + oo];
    v += __shfl_xor(v, 1, 64); v += __shfl_xor(v, 2, 64); v += __shfl_xor(v, 4, 64);
    if (sl == 0) out[ntok + 289 + oo] = v + breg[oo];
  }
}

// ---------------------------------------------------------------------------
__global__ void finalize_A(const float* __restrict__ s_buf, const float* __restrict__ ML,
                           float* __restrict__ out, int ntok){
  int i = blockIdx.x*256 + threadIdx.x;
  if (i < ntok) out[i] = __expf(s_buf[i] - ML[0]) * ML[1];
}

// ---------------------------------------------------------------------------
extern "C" void kernel_launch(void* const* d_in, const int* in_sizes, int n_in,
                              void* d_out, int out_size, void* d_ws, size_t ws_size,
                              hipStream_t stream){
  (void)n_in; (void)out_size; (void)ws_size;
  const float* x    = (const float*)d_in[0];
  const float* W1   = (const float*)d_in[1];
  const float* b1   = (const float*)d_in[2];
  const float* Wa   = (const float*)d_in[3];
  const float* ba   = (const float*)d_in[4];
  const float* Wb   = (const float*)d_in[5];
  const float* bb   = (const float*)d_in[6];
  const float* Wc   = (const float*)d_in[7];
  const float* bc   = (const float*)d_in[8];
  const float* Wr   = (const float*)d_in[9];
  const float* br   = (const float*)d_in[10];
  const float* Wcls = (const float*)d_in[11];
  const float* bcls = (const float*)d_in[12];
  const float* Wreg = (const float*)d_in[13];
  const float* breg = (const float*)d_in[14];
  float* out = (float*)d_out;

  const int ntok   = in_sizes[0] / FEAT;   // 200000
  const int ntiles = ntok / TILE;          // 3125 (exact)

  char* ws = (char*)d_ws;
  float* s_buf = (float*)ws;
  size_t off = (size_t)ntok * 4;                                 // 800000
  float* partials = (float*)(ws + off); off += (size_t)G1*258*4; // +528384
  float* ML = (float*)(ws + off); off += 16;
  unsigned short* W1bf = (unsigned short*)(ws + off); off += (size_t)FEAT*HID*2;
  unsigned short* Wabf = (unsigned short*)(ws + off); off += (size_t)HID*HID*2;
  unsigned short* Wbbf = (unsigned short*)(ws + off); off += (size_t)HID*HID*2;
  // total ws use ~1.86 MB

  prep_weights<<<128, 256, 0, stream>>>(W1, Wa, Wb, W1bf, Wabf, Wbbf);
  fused_main<<<G1, 256, 0, stream>>>(x, b1, ba, bb, Wc, bc, W1bf, Wabf, Wbbf,
                                     s_buf, partials, ntiles);
  reduce_heads<<<1, 1024, 0, stream>>>(partials, Wr, br, Wcls, bcls, Wreg, breg,
                                       out, ML, ntok);
  finalize_A<<<(ntok + 255)/256, 256, 0, stream>>>(s_buf, ML, out, ntok);
}

// Round 5
// 830.101 us; speedup vs baseline: 1.1627x; 1.1627x over previous
//
#include <hip/hip_runtime.h>
#include <stdint.h>

#define FEAT 512
#define HID  256
#define TILE 128
#define G1   256   // fused_main grid = number of partials (1 block/CU)

typedef __attribute__((ext_vector_type(8))) short   short8;
typedef __attribute__((ext_vector_type(4))) float   floatx4;
typedef unsigned int u32;

__device__ inline unsigned short f2bf(float x){
  union { float f; uint32_t u; } v; v.f = x;
  uint32_t u = v.u;
  u += 0x7FFFu + ((u >> 16) & 1u);      // round-to-nearest-even
  return (unsigned short)(u >> 16);
}
__device__ inline float bf2f(unsigned short h){
  union { uint32_t u; float f; } v; v.u = ((uint32_t)h) << 16;
  return v.f;
}
__device__ inline float sigm_f(float x){ return 1.f/(1.f + __expf(-x)); }
__device__ inline float tanh_f(float x){ return 2.f/(1.f + __expf(-2.f*x)) - 1.f; }

__device__ inline short8 pack_bf8(float4 a, float4 b){
  union { short8 v; unsigned short u[8]; } r;
  r.u[0]=f2bf(a.x); r.u[1]=f2bf(a.y); r.u[2]=f2bf(a.z); r.u[3]=f2bf(a.w);
  r.u[4]=f2bf(b.x); r.u[5]=f2bf(b.y); r.u[6]=f2bf(b.z); r.u[7]=f2bf(b.w);
  return r.v;
}

// async global->LDS, 16B per lane; lds dst is wave-uniform (HW adds lane*16)
__device__ __forceinline__ void gl_lds16(const void* g, void* l){
  __builtin_amdgcn_global_load_lds(
      (const __attribute__((address_space(1))) u32*)g,
      (__attribute__((address_space(3))) u32*)l, 16, 0, 0);
}

#define SCHED_FENCE() __builtin_amdgcn_sched_barrier(0)

// ---------------------------------------------------------------------------
// prep: W[K][256] fp32 row-major -> bf16 swizzled to MFMA B-fragment order:
// dst[((kb*16+nt)*64+lane)*8+j] = W[kb*32+(lane>>4)*8+j][nt*16+(lane&15)]
// ---------------------------------------------------------------------------
__global__ void prep_weights(const float* __restrict__ W1, const float* __restrict__ Wa,
                             const float* __restrict__ Wb,
                             unsigned short* __restrict__ W1bf,
                             unsigned short* __restrict__ Wabf,
                             unsigned short* __restrict__ Wbbf){
  int t = blockIdx.x*256 + threadIdx.x;
  const float* src; unsigned short* dst; int g;
  if      (t < 16384){ src = W1; dst = W1bf; g = t; }          // 16 kb * 16 nt * 64
  else if (t < 24576){ src = Wa; dst = Wabf; g = t - 16384; }  // 8 kb
  else if (t < 32768){ src = Wb; dst = Wbbf; g = t - 24576; }  // 8 kb
  else return;
  int lane = g & 63, nt = (g >> 6) & 15, kb = g >> 10;
  int col  = nt*16 + (lane & 15);
  int row0 = kb*32 + (lane >> 4)*8;
  unsigned short* d = dst + (size_t)g*8;
  const float*    s = src + (size_t)row0*HID + col;
  #pragma unroll
  for (int j = 0; j < 8; ++j) d[j] = f2bf(s[(size_t)j*HID]);
}

// ---------------------------------------------------------------------------
// fused_main: 128-token tiles, 4 waves x 32 tokens (two 16-row MFMA strips ->
// every staged weight fragment feeds 2 MFMAs). Double-buffered LDS weight
// staging via global_load_lds + counted vmcnt (never 0 mid-loop).
// ---------------------------------------------------------------------------
__global__ __launch_bounds__(256, 1) void fused_main(
    const float* __restrict__ x,
    const float* __restrict__ b1, const float* __restrict__ ba,
    const float* __restrict__ bb, const float* __restrict__ Wc,
    const float* __restrict__ bc,
    const unsigned short* __restrict__ W1bf,
    const unsigned short* __restrict__ Wabf,
    const unsigned short* __restrict__ Wbbf,
    float* __restrict__ s_buf, float* __restrict__ partials,
    int ntiles, int ntok)
{
  __shared__ alignas(16) unsigned short Hs[128][264];  // 128 tokens x 256 h (+8 pad)
  __shared__ alignas(16) unsigned short Ws[2][8192];   // 2 x 16KB weight staging
  __shared__ float pbuf[4][32];

  const int tid  = threadIdx.x;
  const int wave = tid >> 6, lane = tid & 63;
  const int quad = lane >> 4, l15 = lane & 15;

  float m_run = -INFINITY, l_run = 0.f;
  float g0 = 0.f, g1 = 0.f, g2 = 0.f, g3 = 0.f;   // cols 4*lane .. 4*lane+3
  const float bcv = bc[0];

  for (int t = blockIdx.x; t < ntiles; t += gridDim.x){
    const int tokw0 = t*TILE + wave*32;

    // clamped x row pointers (tail tile reads stay in-bounds; pad rows get p=0)
    int r0 = tokw0 + l15;       if (r0 >= ntok) r0 = ntok - 1;
    int r1 = tokw0 + 16 + l15;  if (r1 >= ntok) r1 = ntok - 1;
    const float* xr0 = x + (size_t)r0*FEAT + quad*8;
    const float* xr1 = x + (size_t)r1*FEAT + quad*8;

    // ---------------- GEMM1: h = relu(x @ W1 + b1), K=512 ----------------
    floatx4 acc0[16], acc1[16];
    #pragma unroll
    for (int nt = 0; nt < 16; ++nt){
      float bv = b1[nt*16 + l15];
      floatx4 tmp = {bv, bv, bv, bv};
      acc0[nt] = tmp; acc1[nt] = tmp;
    }
    SCHED_FENCE();
    // prologue: x(step0) -> A bufs; stage(0) -> Ws[0]; x(step1) -> B bufs
    float4 xA0a = *(const float4*)(xr0),      xA0b = *(const float4*)(xr0 + 4);
    float4 xA1a = *(const float4*)(xr1),      xA1b = *(const float4*)(xr1 + 4);
    SCHED_FENCE();
    #pragma unroll
    for (int c = 0; c < 4; ++c)
      gl_lds16(W1bf + (wave*4 + c)*512 + lane*8, &Ws[0][(wave*4 + c)*512]);
    SCHED_FENCE();
    float4 xB0a = *(const float4*)(xr0 + 32), xB0b = *(const float4*)(xr0 + 36);
    float4 xB1a = *(const float4*)(xr1 + 32), xB1b = *(const float4*)(xr1 + 36);
    SCHED_FENCE();

    #pragma unroll 1
    for (int i = 0; i < 8; ++i){
      const int e = 2*i, o = 2*i + 1;
      // ---- step e: compute Ws[0], stage -> Ws[1] ----
      { const unsigned short* src = W1bf + (size_t)(e+1)*8192;
        #pragma unroll
        for (int c = 0; c < 4; ++c)
          gl_lds16(src + (wave*4 + c)*512 + lane*8, &Ws[1][(wave*4 + c)*512]); }
      SCHED_FENCE();
      asm volatile("s_waitcnt vmcnt(8)" ::: "memory");  // keep stage(e+1)+xB
      __builtin_amdgcn_s_barrier();
      SCHED_FENCE();
      {
        short8 af0 = pack_bf8(xA0a, xA0b);
        short8 af1 = pack_bf8(xA1a, xA1b);
        if (i < 7){
          xA0a = *(const float4*)(xr0 + (e+2)*32); xA0b = *(const float4*)(xr0 + (e+2)*32 + 4);
          xA1a = *(const float4*)(xr1 + (e+2)*32); xA1b = *(const float4*)(xr1 + (e+2)*32 + 4);
        }
        #pragma unroll
        for (int nt = 0; nt < 16; ++nt){
          short8 wf = *(const short8*)(&Ws[0][nt*512 + lane*8]);
          acc0[nt] = __builtin_amdgcn_mfma_f32_16x16x32_bf16(af0, wf, acc0[nt], 0, 0, 0);
          acc1[nt] = __builtin_amdgcn_mfma_f32_16x16x32_bf16(af1, wf, acc1[nt], 0, 0, 0);
        }
      }
      SCHED_FENCE();
      __builtin_amdgcn_s_barrier();
      // ---- step o: compute Ws[1], stage -> Ws[0] ----
      if (i < 7){
        const unsigned short* src = W1bf + (size_t)(o+1)*8192;
        #pragma unroll
        for (int c = 0; c < 4; ++c)
          gl_lds16(src + (wave*4 + c)*512 + lane*8, &Ws[0][(wave*4 + c)*512]);
        SCHED_FENCE();
        asm volatile("s_waitcnt vmcnt(8)" ::: "memory");  // keep stage(o+1)+xA'
      } else {
        SCHED_FENCE();
        asm volatile("s_waitcnt vmcnt(0)" ::: "memory");
      }
      __builtin_amdgcn_s_barrier();
      SCHED_FENCE();
      {
        short8 bf0 = pack_bf8(xB0a, xB0b);
        short8 bf1 = pack_bf8(xB1a, xB1b);
        if (i < 7){
          xB0a = *(const float4*)(xr0 + (o+2)*32); xB0b = *(const float4*)(xr0 + (o+2)*32 + 4);
          xB1a = *(const float4*)(xr1 + (o+2)*32); xB1b = *(const float4*)(xr1 + (o+2)*32 + 4);
        }
        #pragma unroll
        for (int nt = 0; nt < 16; ++nt){
          short8 wf = *(const short8*)(&Ws[1][nt*512 + lane*8]);
          acc0[nt] = __builtin_amdgcn_mfma_f32_16x16x32_bf16(bf0, wf, acc0[nt], 0, 0, 0);
          acc1[nt] = __builtin_amdgcn_mfma_f32_16x16x32_bf16(bf1, wf, acc1[nt], 0, 0, 0);
        }
      }
      SCHED_FENCE();
      __builtin_amdgcn_s_barrier();
    }

    // stage GEMM2 step 0 (Wa/Wb kb=0,nh=0) -> Ws[0], then Hs epilogue (wave-private)
    #pragma unroll
    for (int c = 0; c < 4; ++c){
      int chunk = wave*4 + c;
      const unsigned short* s8 = (chunk < 8) ? (Wabf + chunk*512)
                                             : (Wbbf + (chunk-8)*512);
      gl_lds16(s8 + lane*8, &Ws[0][chunk*512]);
    }
    SCHED_FENCE();
    #pragma unroll
    for (int nt = 0; nt < 16; ++nt){
      #pragma unroll
      for (int r = 0; r < 4; ++r){
        Hs[wave*32 + quad*4 + r][nt*16 + l15]      = f2bf(fmaxf(acc0[nt][r], 0.f));
        Hs[wave*32 + 16 + quad*4 + r][nt*16 + l15] = f2bf(fmaxf(acc1[nt][r], 0.f));
      }
    }

    // ---- GEMM2: a=tanh(h@Wa+ba), b=sigm(h@Wb+bb), s=(a*b)@Wc+bc, K=256 ----
    float s00=0.f,s01=0.f,s02=0.f,s03=0.f, s10=0.f,s11=0.f,s12=0.f,s13=0.f;
    #pragma unroll 1
    for (int nh = 0; nh < 2; ++nh){
      floatx4 aacc0[8], bacc0[8], aacc1[8], bacc1[8];
      #pragma unroll
      for (int nt = 0; nt < 8; ++nt){
        int col = (nh*8 + nt)*16 + l15;
        float av = ba[col], bv = bb[col];
        floatx4 ta = {av, av, av, av};
        floatx4 tb = {bv, bv, bv, bv};
        aacc0[nt] = ta; bacc0[nt] = tb;
        aacc1[nt] = ta; bacc1[nt] = tb;
      }
      #pragma unroll 1
      for (int kb = 0; kb < 8; ++kb){
        int s = nh*8 + kb;                 // global step 0..15, buffer Ws[s&1]
        if (s < 15){
          int s2 = s + 1, nh2 = s2 >> 3, kb2 = s2 & 7;
          const unsigned short* srcA = Wabf + (size_t)(kb2*16 + nh2*8)*512;
          const unsigned short* srcB = Wbbf + (size_t)(kb2*16 + nh2*8)*512;
          unsigned short* dst = Ws[s2 & 1];
          #pragma unroll
          for (int c = 0; c < 4; ++c){
            int chunk = wave*4 + c;
            const unsigned short* s8 = (chunk < 8) ? (srcA + chunk*512)
                                                   : (srcB + (chunk-8)*512);
            gl_lds16(s8 + lane*8, dst + chunk*512);
          }
          SCHED_FENCE();
          asm volatile("s_waitcnt vmcnt(4)" ::: "memory");
        } else {
          SCHED_FENCE();
          asm volatile("s_waitcnt vmcnt(0)" ::: "memory");
        }
        __builtin_amdgcn_s_barrier();
        SCHED_FENCE();
        {
          short8 hf0 = *(const short8*)&Hs[wave*32 + l15][kb*32 + quad*8];
          short8 hf1 = *(const short8*)&Hs[wave*32 + 16 + l15][kb*32 + quad*8];
          const unsigned short* wsb = Ws[s & 1];
          #pragma unroll
          for (int nt = 0; nt < 8; ++nt){
            short8 wfa = *(const short8*)(wsb + nt*512 + lane*8);
            short8 wfb = *(const short8*)(wsb + 4096 + nt*512 + lane*8);
            aacc0[nt] = __builtin_amdgcn_mfma_f32_16x16x32_bf16(hf0, wfa, aacc0[nt], 0, 0, 0);
            bacc0[nt] = __builtin_amdgcn_mfma_f32_16x16x32_bf16(hf0, wfb, bacc0[nt], 0, 0, 0);
            aacc1[nt] = __builtin_amdgcn_mfma_f32_16x16x32_bf16(hf1, wfa, aacc1[nt], 0, 0, 0);
            bacc1[nt] = __builtin_amdgcn_mfma_f32_16x16x32_bf16(hf1, wfb, bacc1[nt], 0, 0, 0);
          }
        }
        SCHED_FENCE();
        __builtin_amdgcn_s_barrier();
      }
      #pragma unroll
      for (int nt = 0; nt < 8; ++nt){
        float wcv = Wc[(nh*8 + nt)*16 + l15];
        s00 += tanh_f(aacc0[nt][0]) * sigm_f(bacc0[nt][0]) * wcv;
        s01 += tanh_f(aacc0[nt][1]) * sigm_f(bacc0[nt][1]) * wcv;
        s02 += tanh_f(aacc0[nt][2]) * sigm_f(bacc0[nt][2]) * wcv;
        s03 += tanh_f(aacc0[nt][3]) * sigm_f(bacc0[nt][3]) * wcv;
        s10 += tanh_f(aacc1[nt][0]) * sigm_f(bacc1[nt][0]) * wcv;
        s11 += tanh_f(aacc1[nt][1]) * sigm_f(bacc1[nt][1]) * wcv;
        s12 += tanh_f(aacc1[nt][2]) * sigm_f(bacc1[nt][2]) * wcv;
        s13 += tanh_f(aacc1[nt][3]) * sigm_f(bacc1[nt][3]) * wcv;
      }
    }
    // reduce s across the 16 lanes of each l15-group (rows = quad*4+r)
    #pragma unroll
    for (int mk = 1; mk < 16; mk <<= 1){
      s00 += __shfl_xor(s00, mk, 64); s01 += __shfl_xor(s01, mk, 64);
      s02 += __shfl_xor(s02, mk, 64); s03 += __shfl_xor(s03, mk, 64);
      s10 += __shfl_xor(s10, mk, 64); s11 += __shfl_xor(s11, mk, 64);
      s12 += __shfl_xor(s12, mk, 64); s13 += __shfl_xor(s13, mk, 64);
    }
    const int base0 = tokw0 + quad*4, base1 = tokw0 + 16 + quad*4;
    s00 = (base0+0 < ntok) ? s00 + bcv : -INFINITY;
    s01 = (base0+1 < ntok) ? s01 + bcv : -INFINITY;
    s02 = (base0+2 < ntok) ? s02 + bcv : -INFINITY;
    s03 = (base0+3 < ntok) ? s03 + bcv : -INFINITY;
    s10 = (base1+0 < ntok) ? s10 + bcv : -INFINITY;
    s11 = (base1+1 < ntok) ? s11 + bcv : -INFINITY;
    s12 = (base1+2 < ntok) ? s12 + bcv : -INFINITY;
    s13 = (base1+3 < ntok) ? s13 + bcv : -INFINITY;
    if (l15 == 0){
      if (base0+0 < ntok) s_buf[base0+0] = s00;
      if (base0+1 < ntok) s_buf[base0+1] = s01;
      if (base0+2 < ntok) s_buf[base0+2] = s02;
      if (base0+3 < ntok) s_buf[base0+3] = s03;
      if (base1+0 < ntok) s_buf[base1+0] = s10;
      if (base1+1 < ntok) s_buf[base1+1] = s11;
      if (base1+2 < ntok) s_buf[base1+2] = s12;
      if (base1+3 < ntok) s_buf[base1+3] = s13;
    }
    // online softmax update (per wave)
    float tmax = fmaxf(fmaxf(fmaxf(s00, s01), fmaxf(s02, s03)),
                       fmaxf(fmaxf(s10, s11), fmaxf(s12, s13)));
    tmax = fmaxf(tmax, __shfl_xor(tmax, 16, 64));
    tmax = fmaxf(tmax, __shfl_xor(tmax, 32, 64));
    float m_new = fmaxf(m_run, tmax);
    float alpha = __expf(m_run - m_new);       // exp(-inf)=0 on first tile
    float p00 = __expf(s00 - m_new), p01 = __expf(s01 - m_new);
    float p02 = __expf(s02 - m_new), p03 = __expf(s03 - m_new);
    float p10 = __expf(s10 - m_new), p11 = __expf(s11 - m_new);
    float p12 = __expf(s12 - m_new), p13 = __expf(s13 - m_new);
    float psum = p00 + p01 + p02 + p03 + p10 + p11 + p12 + p13;
    psum += __shfl_xor(psum, 16, 64);
    psum += __shfl_xor(psum, 32, 64);
    l_run = l_run*alpha + psum;
    m_run = m_new;
    if (l15 == 0){
      pbuf[wave][quad*4+0]    = p00; pbuf[wave][quad*4+1]    = p01;
      pbuf[wave][quad*4+2]    = p02; pbuf[wave][quad*4+3]    = p03;
      pbuf[wave][16+quad*4+0] = p10; pbuf[wave][16+quad*4+1] = p11;
      pbuf[wave][16+quad*4+2] = p12; pbuf[wave][16+quad*4+3] = p13;
    }
    g0 *= alpha; g1 *= alpha; g2 *= alpha; g3 *= alpha;
    #pragma unroll
    for (int rw = 0; rw < 32; ++rw){
      float pr = pbuf[wave][rw];
      const unsigned short* hp = &Hs[wave*32 + rw][lane*4];
      g0 += pr*bf2f(hp[0]); g1 += pr*bf2f(hp[1]);
      g2 += pr*bf2f(hp[2]); g3 += pr*bf2f(hp[3]);
    }
  }

  // ---- combine 4 waves -> per-workgroup partial {M, L, g[256]} ----
  __syncthreads();
  float* fred = (float*)Ws;                    // reuse staging LDS
  if (lane == 0) fred[wave] = m_run;
  __syncthreads();
  float M = fmaxf(fmaxf(fred[0], fred[1]), fmaxf(fred[2], fred[3]));
  float sc = (m_run == -INFINITY) ? 0.f : __expf(m_run - M);
  if (lane == 0) fred[4 + wave] = l_run * sc;
  fred[8 + wave*256 + lane*4 + 0] = g0*sc;
  fred[8 + wave*256 + lane*4 + 1] = g1*sc;
  fred[8 + wave*256 + lane*4 + 2] = g2*sc;
  fred[8 + wave*256 + lane*4 + 3] = g3*sc;
  __syncthreads();
  float gsum = fred[8 + 0*256 + tid] + fred[8 + 1*256 + tid]
             + fred[8 + 2*256 + tid] + fred[8 + 3*256 + tid];
  float* P = partials + (size_t)blockIdx.x*258;
  if (tid == 0){ P[0] = M; P[1] = fred[4] + fred[5] + fred[6] + fred[7]; }
  P[2 + tid] = gsum;
}

// ---------------------------------------------------------------------------
// reduce_heads: combine G1 partials -> M, L, global_feat; then hr/cls/reg
// heads in exact fp32. 1024 threads, split-K parallel matvecs.
// ---------------------------------------------------------------------------
__global__ __launch_bounds__(1024) void reduce_heads(const float* __restrict__ partials,
    const float* __restrict__ Wr,   const float* __restrict__ br,
    const float* __restrict__ Wcls, const float* __restrict__ bcls,
    const float* __restrict__ Wreg, const float* __restrict__ breg,
    float* __restrict__ out, float* __restrict__ ML, int ntok)
{
  __shared__ float red[1024];
  __shared__ float scw[G1];
  __shared__ float gf[256];
  __shared__ float hr[256];
  const int t = threadIdx.x;

  float lm = -INFINITY;
  for (int i = t; i < G1; i += 1024) lm = fmaxf(lm, partials[(size_t)i*258]);
  red[t] = lm; __syncthreads();
  for (int s = 512; s > 0; s >>= 1){ if (t < s) red[t] = fmaxf(red[t], red[t+s]); __syncthreads(); }
  float M = red[0];
  __syncthreads();

  float ll = 0.f;
  for (int i = t; i < G1; i += 1024){
    float w = __expf(partials[(size_t)i*258] - M);
    scw[i] = w;
    ll += partials[(size_t)i*258 + 1] * w;
  }
  red[t] = ll; __syncthreads();
  for (int s = 512; s > 0; s >>= 1){ if (t < s) red[t] += red[t+s]; __syncthreads(); }
  float L = red[0];
  __syncthreads();

  const int col = t & 255, grp = t >> 8;
  float g = 0.f;
  #pragma unroll 4
  for (int i = grp; i < G1; i += 4) g += partials[(size_t)i*258 + 2 + col] * scw[i];
  red[t] = g; __syncthreads();
  if (grp == 0){
    float gfv = (red[col] + red[256+col] + red[512+col] + red[768+col]) / L;
    gf[col] = gfv;
    out[ntok + col] = gfv;
    if (col == 0){ ML[0] = M; ML[1] = 1.f / L; }
  }
  __syncthreads();

  float h = 0.f;
  #pragma unroll 8
  for (int c = grp*64; c < grp*64 + 64; ++c) h += gf[c] * Wr[(size_t)c*256 + col];
  red[t] = h; __syncthreads();
  if (grp == 0){
    float hv = red[col] + red[256+col] + red[512+col] + red[768+col] + br[col];
    hr[col] = fmaxf(hv, 0.f);
  }
  __syncthreads();

  const int o = t >> 3, sl = t & 7;
  if (o < 33){
    float v = 0.f;
    #pragma unroll 8
    for (int j = sl; j < 256; j += 8) v += hr[j] * Wcls[(size_t)j*33 + o];
    v += __shfl_xor(v, 1, 64); v += __shfl_xor(v, 2, 64); v += __shfl_xor(v, 4, 64);
    if (sl == 0) out[ntok + 256 + o] = v + bcls[o];
  } else if (o >= 64 && o < 64 + 55){
    int oo = o - 64;
    float v = 0.f;
    #pragma unroll 8
    for (int j = sl; j < 256; j += 8) v += hr[j] * Wreg[(size_t)j*55 + oo];
    v += __shfl_xor(v, 1, 64); v += __shfl_xor(v, 2, 64); v += __shfl_xor(v, 4, 64);
    if (sl == 0) out[ntok + 289 + oo] = v + breg[oo];
  }
}

// ---------------------------------------------------------------------------
__global__ void finalize_A(const float* __restrict__ s_buf, const float* __restrict__ ML,
                           float* __restrict__ out, int ntok){
  int i = blockIdx.x*256 + threadIdx.x;
  if (i < ntok) out[i] = __expf(s_buf[i] - ML[0]) * ML[1];
}

// ---------------------------------------------------------------------------
extern "C" void kernel_launch(void* const* d_in, const int* in_sizes, int n_in,
                              void* d_out, int out_size, void* d_ws, size_t ws_size,
                              hipStream_t stream){
  (void)n_in; (void)out_size; (void)ws_size;
  const float* x    = (const float*)d_in[0];
  const float* W1   = (const float*)d_in[1];
  const float* b1   = (const float*)d_in[2];
  const float* Wa   = (const float*)d_in[3];
  const float* ba   = (const float*)d_in[4];
  const float* Wb   = (const float*)d_in[5];
  const float* bb   = (const float*)d_in[6];
  const float* Wc   = (const float*)d_in[7];
  const float* bc   = (const float*)d_in[8];
  const float* Wr   = (const float*)d_in[9];
  const float* br   = (const float*)d_in[10];
  const float* Wcls = (const float*)d_in[11];
  const float* bcls = (const float*)d_in[12];
  const float* Wreg = (const float*)d_in[13];
  const float* breg = (const float*)d_in[14];
  float* out = (float*)d_out;

  const int ntok   = in_sizes[0] / FEAT;              // 200000
  const int ntiles = (ntok + TILE - 1) / TILE;        // 1563 (last tile padded)

  char* ws = (char*)d_ws;
  float* s_buf = (float*)ws;
  size_t off = (size_t)ntok * 4;                                 // 800000
  float* partials = (float*)(ws + off); off += (size_t)G1*258*4; // +264192
  float* ML = (float*)(ws + off); off += 16;
  unsigned short* W1bf = (unsigned short*)(ws + off); off += (size_t)FEAT*HID*2;
  unsigned short* Wabf = (unsigned short*)(ws + off); off += (size_t)HID*HID*2;
  unsigned short* Wbbf = (unsigned short*)(ws + off); off += (size_t)HID*HID*2;
  // total ws use ~1.6 MB

  prep_weights<<<128, 256, 0, stream>>>(W1, Wa, Wb, W1bf, Wabf, Wbbf);
  fused_main<<<G1, 256, 0, stream>>>(x, b1, ba, bb, Wc, bc, W1bf, Wabf, Wbbf,
                                     s_buf, partials, ntiles, ntok);
  reduce_heads<<<1, 1024, 0, stream>>>(partials, Wr, br, Wcls, bcls, Wreg, breg,
                                       out, ML, ntok);
  finalize_A<<<(ntok + 255)/256, 256, 0, stream>>>(s_buf, ML, out, ntok);
}